// Round 1
// baseline (323.746 us; speedup 1.0000x reference)
//
#include <hip/hip_runtime.h>

#define Bv 1024
#define Tv 512
#define Kv 64
#define WPB 4   // waves (sequences) per block

__global__ __launch_bounds__(256) void crf_fwd_kernel(
    const float* __restrict__ x,      // [B,T,K]
    const int*   __restrict__ y,      // [T,B]
    const float* __restrict__ trans,  // [K,K]
    const float* __restrict__ startv, // [K]
    const float* __restrict__ endv,   // [K]
    float* __restrict__ out_b)        // [B] per-sequence (logZ - num)
{
    __shared__ float Es[Kv * Kv];   // exp(trans)
    __shared__ float TRs[Kv * Kv];  // raw trans (for numerator)
    __shared__ float ea_s[WPB][Kv]; // per-wave exp(alpha - m) staging

    const int tid = threadIdx.x;
    for (int i = tid; i < Kv * Kv; i += 256) {
        float tv = trans[i];
        TRs[i] = tv;
        Es[i]  = __expf(tv);
    }
    __syncthreads();

    const int wave = tid >> 6;
    const int lane = tid & 63;
    const int b = blockIdx.x * WPB + wave;

    // Column k=lane of E into registers (statically indexed -> stays in VGPRs)
    float Ereg[Kv];
    #pragma unroll
    for (int j = 0; j < Kv; ++j) Ereg[j] = Es[j * Kv + lane];

    const int xoff = b * (Tv * Kv) + lane;

    // t = 0
    float xv = x[xoff];
    float alpha = startv[lane] + xv;
    const int y0 = y[b];            // y[0*B + b], wave-uniform
    int   ycur = y0;
    float emit = (lane == ycur) ? xv : 0.f;
    float trc  = 0.f;               // wave-uniform transition-score accumulator

    // software prefetch one step ahead
    float xnext = x[xoff + Kv];
    int   ynext = y[Bv + b];

    for (int t = 1; t < Tv; ++t) {
        float xcur = xnext;
        int   yt   = ynext;
        if (t + 1 < Tv) {
            xnext = x[xoff + (t + 1) * Kv];
            ynext = y[(t + 1) * Bv + b];
        }

        // wave max of alpha
        float m = alpha;
        #pragma unroll
        for (int off = 32; off > 0; off >>= 1)
            m = fmaxf(m, __shfl_xor(m, off, 64));

        float ea = __expf(alpha - m);
        ea_s[wave][lane] = ea;  // wave-private slot; compiler inserts lgkmcnt wait

        // s[lane] = sum_j ea[j] * E[j][lane]; broadcast float4 reads of ea
        float s0 = 0.f, s1 = 0.f, s2 = 0.f, s3 = 0.f;
        #pragma unroll
        for (int j = 0; j < Kv; j += 4) {
            float4 e4 = *(const float4*)&ea_s[wave][j];
            s0 = fmaf(e4.x, Ereg[j + 0], s0);
            s1 = fmaf(e4.y, Ereg[j + 1], s1);
            s2 = fmaf(e4.z, Ereg[j + 2], s2);
            s3 = fmaf(e4.w, Ereg[j + 3], s3);
        }
        alpha = m + __logf((s0 + s1) + (s2 + s3)) + xcur;

        // numerator pieces
        emit += (lane == yt) ? xcur : 0.f;
        trc  += TRs[ycur * Kv + yt];  // uniform broadcast read
        ycur = yt;
    }

    // logZ = logsumexp_k(alpha + end)
    float a2 = alpha + endv[lane];
    float m = a2;
    #pragma unroll
    for (int off = 32; off > 0; off >>= 1)
        m = fmaxf(m, __shfl_xor(m, off, 64));
    float es = __expf(a2 - m);
    float sum = es;
    #pragma unroll
    for (int off = 32; off > 0; off >>= 1)
        sum += __shfl_xor(sum, off, 64);
    float logZ = m + __logf(sum);

    // reduce per-lane emission contributions
    float esum = emit;
    #pragma unroll
    for (int off = 32; off > 0; off >>= 1)
        esum += __shfl_xor(esum, off, 64);

    float num = esum + trc + startv[y0] + endv[ycur];
    if (lane == 0) out_b[b] = logZ - num;
}

__global__ __launch_bounds__(256) void crf_reduce_kernel(
    const float* __restrict__ in, float* __restrict__ out)
{
    const int tid = threadIdx.x;
    float v = 0.f;
    for (int i = tid; i < Bv; i += 256) v += in[i];
    #pragma unroll
    for (int off = 32; off > 0; off >>= 1) v += __shfl_xor(v, off, 64);
    __shared__ float ws[4];
    if ((tid & 63) == 0) ws[tid >> 6] = v;
    __syncthreads();
    if (tid == 0) out[0] = ws[0] + ws[1] + ws[2] + ws[3];
}

extern "C" void kernel_launch(void* const* d_in, const int* in_sizes, int n_in,
                              void* d_out, int out_size, void* d_ws, size_t ws_size,
                              hipStream_t stream) {
    const float* x      = (const float*)d_in[0];
    // d_in[1] = seq_len (all == T, unused by reference math)
    const int*   y      = (const int*)d_in[2];
    const float* trans  = (const float*)d_in[3];
    const float* startv = (const float*)d_in[4];
    const float* endv   = (const float*)d_in[5];
    float* out  = (float*)d_out;
    float* wsb  = (float*)d_ws;   // [B] per-sequence results

    hipLaunchKernelGGL(crf_fwd_kernel, dim3(Bv / WPB), dim3(256), 0, stream,
                       x, y, trans, startv, endv, wsb);
    hipLaunchKernelGGL(crf_reduce_kernel, dim3(1), dim3(256), 0, stream, wsb, out);
}

// Round 2
// 305.158 us; speedup vs baseline: 1.0609x; 1.0609x over previous
//
#include <hip/hip_runtime.h>

#define Bv 1024
#define Tv 512
#define Kv 64
#define WPB 4
#define LN2 0.69314718055994530942f

__global__ __launch_bounds__(256) void crf_fwd_kernel(
    const float* __restrict__ x,      // [B,T,K]
    const int*   __restrict__ y,      // [T,B]
    const float* __restrict__ trans,  // [K,K]
    const float* __restrict__ startv, // [K]
    const float* __restrict__ endv,   // [K]
    float* __restrict__ out_b)        // [B]
{
    __shared__ __align__(16) float Es[Kv * Kv];   // exp(trans)
    __shared__ float TRs[Kv * Kv];                // raw trans (numerator)
    __shared__ __align__(16) float ea_s[WPB][Kv]; // per-wave exp(alpha - C)

    const int tid = threadIdx.x;
    for (int i = tid; i < Kv * Kv; i += 256) {
        float tv = trans[i];
        TRs[i] = tv;
        Es[i]  = __expf(tv);
    }
    __syncthreads();

    const int wave = tid >> 6;
    const int lane = tid & 63;
    const int b = blockIdx.x * WPB + wave;

    // Column k=lane of E into registers (statically indexed -> VGPRs)
    float Ereg[Kv];
    #pragma unroll
    for (int j = 0; j < Kv; ++j) Ereg[j] = Es[j * Kv + lane];

    const float* xb = x + (size_t)b * (Tv * Kv) + lane;

    // ---- t = 0 ----
    float x0 = xb[0];
    float a0 = startv[lane] + x0;
    float Chat = __uint_as_float(__builtin_amdgcn_readfirstlane(__float_as_uint(a0)));
    float eacur = __expf(a0 - Chat);   // exp(alpha0 - C0), C0 = lane0's alpha0
    ea_s[wave][lane] = eacur;
    float xhat_sum = Chat;             // running C (float part)
    int   esum = 0;                    // running C (power-of-2 part, in units of ln2)

    const int y0 = y[b];
    int   ycur = y0;
    float emit = (lane == y0) ? x0 : 0.f;
    float trc  = 0.f;

    // ---- prefetch slots: A = odd t, B = even t (depth 2) ----
    float XA, QA, XHA; int YA;
    float XB, QB, XHB; int YB;
    {
        float xv = xb[1 * Kv];
        float xh = __uint_as_float(__builtin_amdgcn_readfirstlane(__float_as_uint(xv)));
        XA = xv; XHA = xh; QA = __expf(xv - xh); YA = y[1 * Bv + b];
        xv = xb[2 * Kv];
        xh = __uint_as_float(__builtin_amdgcn_readfirstlane(__float_as_uint(xv)));
        XB = xv; XHB = xh; QB = __expf(xv - xh); YB = y[2 * Bv + b];
    }

#define CRF_STEP(T_, XC, QC, XHC, YC)                                            \
    {                                                                            \
        const float xcur = XC; const float qcur = QC;                            \
        const float xh   = XHC; const int  yt  = YC;                             \
        if ((T_) + 2 < Tv) {  /* prefetch t+2 into same slot (off-chain) */      \
            float xv  = xb[((T_) + 2) * Kv];                                     \
            float xh2 = __uint_as_float(                                         \
                __builtin_amdgcn_readfirstlane(__float_as_uint(xv)));            \
            XC = xv; XHC = xh2; QC = __expf(xv - xh2);                           \
            YC = y[((T_) + 2) * Bv + b];                                         \
        }                                                                        \
        float s0 = 0.f, s1 = 0.f, s2 = 0.f, s3 = 0.f;                            \
        _Pragma("unroll")                                                        \
        for (int j = 0; j < Kv; j += 4) {                                        \
            float4 e4 = *(const float4*)&ea_s[wave][j];  /* broadcast read */    \
            s0 = fmaf(e4.x, Ereg[j + 0], s0);                                    \
            s1 = fmaf(e4.y, Ereg[j + 1], s1);                                    \
            s2 = fmaf(e4.z, Ereg[j + 2], s2);                                    \
            s3 = fmaf(e4.w, Ereg[j + 3], s3);                                    \
        }                                                                        \
        float ssum = (s0 + s1) + (s2 + s3);                                      \
        unsigned sb = __builtin_amdgcn_readfirstlane(__float_as_uint(ssum));     \
        int e = (int)((sb >> 23) & 0xFFu);                                       \
        esum += e - 127;                                                         \
        float mult = __uint_as_float((unsigned)(254 - e) << 23); /* 2^(127-e) */ \
        eacur = ssum * qcur * mult;  /* exp(alpha' - C') */                      \
        ea_s[wave][lane] = eacur;                                                \
        xhat_sum += xh;                                                          \
        emit += (lane == yt) ? xcur : 0.f;                                       \
        trc  += TRs[ycur * Kv + yt];                                             \
        ycur = yt;                                                               \
    }

    for (int t = 1; t + 1 < Tv; t += 2) {
        CRF_STEP(t,     XA, QA, XHA, YA);
        CRF_STEP(t + 1, XB, QB, XHB, YB);
    }
    CRF_STEP(Tv - 1, XA, QA, XHA, YA);   // Tv-1 = 511, odd -> slot A
#undef CRF_STEP

    // ---- logZ = C + log(sum_k ea_k * exp(end_k)) ----
    float val = eacur * __expf(endv[lane]);
    float sum = val;
    #pragma unroll
    for (int off = 32; off > 0; off >>= 1) sum += __shfl_xor(sum, off, 64);
    float logZ = __logf(sum) + xhat_sum + LN2 * (float)esum;

    float esumv = emit;
    #pragma unroll
    for (int off = 32; off > 0; off >>= 1) esumv += __shfl_xor(esumv, off, 64);

    float num = esumv + trc + startv[y0] + endv[ycur];
    if (lane == 0) out_b[b] = logZ - num;
}

__global__ __launch_bounds__(256) void crf_reduce_kernel(
    const float* __restrict__ in, float* __restrict__ out)
{
    const int tid = threadIdx.x;
    float v = 0.f;
    for (int i = tid; i < Bv; i += 256) v += in[i];
    #pragma unroll
    for (int off = 32; off > 0; off >>= 1) v += __shfl_xor(v, off, 64);
    __shared__ float ws[4];
    if ((tid & 63) == 0) ws[tid >> 6] = v;
    __syncthreads();
    if (tid == 0) out[0] = ws[0] + ws[1] + ws[2] + ws[3];
}

extern "C" void kernel_launch(void* const* d_in, const int* in_sizes, int n_in,
                              void* d_out, int out_size, void* d_ws, size_t ws_size,
                              hipStream_t stream) {
    const float* x      = (const float*)d_in[0];
    // d_in[1] = seq_len (all == T; unused by the reference math)
    const int*   y      = (const int*)d_in[2];
    const float* trans  = (const float*)d_in[3];
    const float* startv = (const float*)d_in[4];
    const float* endv   = (const float*)d_in[5];
    float* out = (float*)d_out;
    float* wsb = (float*)d_ws;   // [B] per-sequence results

    hipLaunchKernelGGL(crf_fwd_kernel, dim3(Bv / WPB), dim3(256), 0, stream,
                       x, y, trans, startv, endv, wsb);
    hipLaunchKernelGGL(crf_reduce_kernel, dim3(1), dim3(256), 0, stream, wsb, out);
}

// Round 3
// 156.735 us; speedup vs baseline: 2.0656x; 1.9470x over previous
//
#include <hip/hip_runtime.h>

#define Bv 1024
#define Tv 512
#define Kv 64
#define WPB 4
#define LN2 0.69314718055994530942f

typedef float v2f __attribute__((ext_vector_type(2)));

__global__ __launch_bounds__(256) void crf_fwd_kernel(
    const float* __restrict__ x,      // [B,T,K]
    const int*   __restrict__ y,      // [T,B]
    const float* __restrict__ trans,  // [K,K]
    const float* __restrict__ startv, // [K]
    const float* __restrict__ endv,   // [K]
    float* __restrict__ out_b)        // [B]
{
    __shared__ __align__(16) float Es[Kv * Kv];   // exp(trans)
    __shared__ float TRs[Kv * Kv];                // raw trans (numerator)
    __shared__ __align__(16) float ea_s[WPB][Kv]; // per-wave scaled exp(alpha)

    const int tid = threadIdx.x;
    for (int i = tid; i < Kv * Kv; i += 256) {
        float tv = trans[i];
        TRs[i] = tv;
        Es[i]  = __expf(tv);
    }
    __syncthreads();

    const int wave = tid >> 6;
    const int lane = tid & 63;
    const int b = blockIdx.x * WPB + wave;

    // Column k=lane of E as 32 float2 pairs (64 VGPRs, statically indexed)
    v2f Er2[Kv / 2];
    #pragma unroll
    for (int j = 0; j < Kv; j += 2) {
        Er2[j / 2][0] = Es[(j + 0) * Kv + lane];
        Er2[j / 2][1] = Es[(j + 1) * Kv + lane];
    }

    const float* xb = x + (size_t)b * (Tv * Kv) + lane;

    // ---- t = 0 init ----
    float x0v = xb[0];
    float eacur = __expf(startv[lane] + x0v);   // scaled alpha, scale tracked in esum
    ea_s[wave][lane] = eacur;
    const int y0 = y[b];
    int   ycur = y0;
    float emit = (lane == y0) ? x0v : 0.f;
    float trc  = 0.f;
    int   esum = 0;                             // wave-uniform: units of log(2)

    // ---- 4-deep pipeline state (all statically indexed -> registers) ----
    float q[4], raw[4], xc[4];
    int   yq[4], yraw[4];
    #pragma unroll
    for (int i = 0; i < 4; ++i) {
        float xv = xb[(1 + i) * Kv];
        xc[i] = xv; q[i] = __expf(xv);
        raw[i]  = xb[(5 + i) * Kv];
        yq[i]   = y[(1 + i) * Bv + b];
        yraw[i] = y[(5 + i) * Bv + b];
    }

#define MATVEC(QV)                                                       \
    {                                                                    \
        v2f a0 = {0,0}, a1 = {0,0}, a2 = {0,0}, a3 = {0,0};              \
        _Pragma("unroll")                                                \
        for (int j = 0; j < Kv; j += 8) {                                \
            float4 e4a = *(const float4*)&ea_s[wave][j];                 \
            float4 e4b = *(const float4*)&ea_s[wave][j + 4];             \
            a0 = __builtin_elementwise_fma((v2f){e4a.x, e4a.y},          \
                                           Er2[j/2 + 0], a0);            \
            a1 = __builtin_elementwise_fma((v2f){e4a.z, e4a.w},          \
                                           Er2[j/2 + 1], a1);            \
            a2 = __builtin_elementwise_fma((v2f){e4b.x, e4b.y},          \
                                           Er2[j/2 + 2], a2);            \
            a3 = __builtin_elementwise_fma((v2f){e4b.z, e4b.w},          \
                                           Er2[j/2 + 3], a3);            \
        }                                                                \
        v2f aa = (a0 + a1) + (a2 + a3);                                  \
        eacur = (aa[0] + aa[1]) * (QV);                                  \
    }

    // main groups: t = 1,5,...,505 cover steps 1..508
    for (int t = 1; t <= Tv - 7; t += 4) {
        #pragma unroll
        for (int i = 0; i < 4; ++i) {
            const float xcur = xc[i];
            const int   yt   = yq[i];
            MATVEC(q[i]);
            if (i == 3) {  // renormalize every 4th step by lane0's exponent
                unsigned sb = __builtin_amdgcn_readfirstlane(__float_as_uint(eacur));
                int e = (int)((sb >> 23) & 0xFFu);
                esum += e - 127;
                eacur *= __uint_as_float((unsigned)(254 - e) << 23); // *2^(127-e)
            }
            ea_s[wave][lane] = eacur;
            // off-chain: numerator pieces
            emit += (lane == yt) ? xcur : 0.f;
            trc  += TRs[ycur * Kv + yt];
            ycur = yt;
            // off-chain: pipeline advance (consume-before-overwrite)
            xc[i] = raw[i];
            q[i]  = __expf(raw[i]);
            int idx = t + 8 + i; if (idx > Tv - 1) idx = Tv - 1;   // clamped tail loads (dead)
            raw[i]  = xb[idx * Kv];
            yq[i]   = yraw[i];
            yraw[i] = y[idx * Bv + b];
        }
    }
    // epilogue: steps 509,510,511
    #pragma unroll
    for (int i = 0; i < 3; ++i) {
        const float xcur = xc[i];
        const int   yt   = yq[i];
        MATVEC(q[i]);
        ea_s[wave][lane] = eacur;
        emit += (lane == yt) ? xcur : 0.f;
        trc  += TRs[ycur * Kv + yt];
        ycur = yt;
    }
#undef MATVEC

    // ---- logZ = log2-scale + log(sum_k ea_k * exp(end_k)) ----
    float val = eacur * __expf(endv[lane]);
    float sum = val;
    #pragma unroll
    for (int off = 32; off > 0; off >>= 1) sum += __shfl_xor(sum, off, 64);
    float logZ = __logf(sum) + LN2 * (float)esum;

    float esumv = emit;
    #pragma unroll
    for (int off = 32; off > 0; off >>= 1) esumv += __shfl_xor(esumv, off, 64);

    float num = esumv + trc + startv[y0] + endv[ycur];
    if (lane == 0) out_b[b] = logZ - num;
}

__global__ __launch_bounds__(256) void crf_reduce_kernel(
    const float* __restrict__ in, float* __restrict__ out)
{
    const int tid = threadIdx.x;
    float v = 0.f;
    for (int i = tid; i < Bv; i += 256) v += in[i];
    #pragma unroll
    for (int off = 32; off > 0; off >>= 1) v += __shfl_xor(v, off, 64);
    __shared__ float ws[4];
    if ((tid & 63) == 0) ws[tid >> 6] = v;
    __syncthreads();
    if (tid == 0) out[0] = ws[0] + ws[1] + ws[2] + ws[3];
}

extern "C" void kernel_launch(void* const* d_in, const int* in_sizes, int n_in,
                              void* d_out, int out_size, void* d_ws, size_t ws_size,
                              hipStream_t stream) {
    const float* x      = (const float*)d_in[0];
    // d_in[1] = seq_len (all == T; unused by the reference math)
    const int*   y      = (const int*)d_in[2];
    const float* trans  = (const float*)d_in[3];
    const float* startv = (const float*)d_in[4];
    const float* endv   = (const float*)d_in[5];
    float* out = (float*)d_out;
    float* wsb = (float*)d_ws;   // [B] per-sequence results

    hipLaunchKernelGGL(crf_fwd_kernel, dim3(Bv / WPB), dim3(256), 0, stream,
                       x, y, trans, startv, endv, wsb);
    hipLaunchKernelGGL(crf_reduce_kernel, dim3(1), dim3(256), 0, stream, wsb, out);
}